// Round 1
// baseline (100.066 us; speedup 1.0000x reference)
//
#include <hip/hip_runtime.h>

constexpr int NSAMP = 32768;
constexpr int DIM   = 2048;
constexpr int NCLS  = 512;
constexpr double EPS = 1e-6;

// ws layout (byte offsets):
//   0      : double acc[2]  {Q = sum x^2, T3 = sum_c |S_c|^2/count_c}
//   64     : int counts[512]
//   2112   : int cursors[512]
//   4160   : int offsets[512]
//   8192   : int idx_list[32768]
// total ~139 KB

__global__ void k_init(double* acc, int* counts, int* cursors) {
    int t = threadIdx.x;
    if (t < 2) acc[t] = 0.0;
    for (int i = t; i < NCLS; i += 256) { counts[i] = 0; cursors[i] = 0; }
}

__global__ void k_hist(const int* __restrict__ label, int* __restrict__ counts) {
    int i = blockIdx.x * blockDim.x + threadIdx.x;
    if (i < NSAMP) atomicAdd(&counts[label[i]], 1);
}

__global__ void k_scan(const int* __restrict__ counts, int* __restrict__ offsets) {
    __shared__ int s[NCLS];
    int t = threadIdx.x;
    s[t] = counts[t];
    __syncthreads();
    // Hillis-Steele inclusive scan
    for (int off = 1; off < NCLS; off <<= 1) {
        int v = (t >= off) ? s[t - off] : 0;
        __syncthreads();
        s[t] += v;
        __syncthreads();
    }
    offsets[t] = s[t] - counts[t];  // exclusive
}

__global__ void k_fill(const int* __restrict__ label, const int* __restrict__ offsets,
                       int* __restrict__ cursors, int* __restrict__ idx_list) {
    int i = blockIdx.x * blockDim.x + threadIdx.x;
    if (i < NSAMP) {
        int c = label[i];
        int p = atomicAdd(&cursors[c], 1);
        idx_list[offsets[c] + p] = i;
    }
}

// grid = (DIM/1024, NCLS), block = 256. Each thread owns 4 contiguous columns
// (float4); block (bx, c) gathers all rows of class c over its 1024-column slice.
// Every element of x is read exactly once across the whole grid.
__global__ void __launch_bounds__(256) k_main(const float* __restrict__ x,
                                              const int* __restrict__ counts,
                                              const int* __restrict__ offsets,
                                              const int* __restrict__ idx_list,
                                              double* __restrict__ acc) {
    const int c    = blockIdx.y;
    const int cnt  = counts[c];
    const int base = offsets[c];
    const float* xp = x + (size_t)blockIdx.x * 1024 + threadIdx.x * 4;

    float Sx = 0.f, Sy = 0.f, Sz = 0.f, Sw = 0.f;  // per-column class-sum frags
    float Q  = 0.f;                                 // sum of squares

    int r = 0;
    for (; r + 4 <= cnt; r += 4) {
        const int i0 = idx_list[base + r + 0];
        const int i1 = idx_list[base + r + 1];
        const int i2 = idx_list[base + r + 2];
        const int i3 = idx_list[base + r + 3];
        const float4 a = *reinterpret_cast<const float4*>(xp + (size_t)i0 * DIM);
        const float4 b = *reinterpret_cast<const float4*>(xp + (size_t)i1 * DIM);
        const float4 e = *reinterpret_cast<const float4*>(xp + (size_t)i2 * DIM);
        const float4 f = *reinterpret_cast<const float4*>(xp + (size_t)i3 * DIM);
        Sx += a.x + b.x + e.x + f.x;
        Sy += a.y + b.y + e.y + f.y;
        Sz += a.z + b.z + e.z + f.z;
        Sw += a.w + b.w + e.w + f.w;
        Q += a.x*a.x + a.y*a.y + a.z*a.z + a.w*a.w;
        Q += b.x*b.x + b.y*b.y + b.z*b.z + b.w*b.w;
        Q += e.x*e.x + e.y*e.y + e.z*e.z + e.w*e.w;
        Q += f.x*f.x + f.y*f.y + f.z*f.z + f.w*f.w;
    }
    for (; r < cnt; ++r) {
        const int i0 = idx_list[base + r];
        const float4 a = *reinterpret_cast<const float4*>(xp + (size_t)i0 * DIM);
        Sx += a.x; Sy += a.y; Sz += a.z; Sw += a.w;
        Q += a.x*a.x + a.y*a.y + a.z*a.z + a.w*a.w;
    }

    double t3 = 0.0;
    if (cnt > 0) {
        double s2 = (double)Sx*(double)Sx + (double)Sy*(double)Sy
                  + (double)Sz*(double)Sz + (double)Sw*(double)Sw;
        t3 = s2 / (double)cnt;
    }
    double q = (double)Q;

    __shared__ double sq[256];
    __shared__ double st[256];
    sq[threadIdx.x] = q;
    st[threadIdx.x] = t3;
    __syncthreads();
    for (int o = 128; o > 0; o >>= 1) {
        if (threadIdx.x < o) {
            sq[threadIdx.x] += sq[threadIdx.x + o];
            st[threadIdx.x] += st[threadIdx.x + o];
        }
        __syncthreads();
    }
    if (threadIdx.x == 0) {
        atomicAdd(&acc[0], sq[0]);
        atomicAdd(&acc[1], st[0]);
    }
}

__global__ void k_final(const double* __restrict__ acc, float* __restrict__ out) {
    // loss = (Q - T3)/N + D*eps^2   (the 2*eps linear term cancels exactly)
    double res = (acc[0] - acc[1]) / (double)NSAMP + (double)DIM * EPS * EPS;
    out[0] = (float)res;
}

extern "C" void kernel_launch(void* const* d_in, const int* in_sizes, int n_in,
                              void* d_out, int out_size, void* d_ws, size_t ws_size,
                              hipStream_t stream) {
    const float* x     = (const float*)d_in[0];
    const int*   label = (const int*)d_in[1];
    float*       out   = (float*)d_out;

    char* ws = (char*)d_ws;
    double* acc    = (double*)(ws + 0);
    int* counts    = (int*)(ws + 64);
    int* cursors   = (int*)(ws + 2112);
    int* offsets   = (int*)(ws + 4160);
    int* idx_list  = (int*)(ws + 8192);

    hipLaunchKernelGGL(k_init, dim3(1), dim3(256), 0, stream, acc, counts, cursors);
    hipLaunchKernelGGL(k_hist, dim3(NSAMP / 512), dim3(512), 0, stream, label, counts);
    hipLaunchKernelGGL(k_scan, dim3(1), dim3(NCLS), 0, stream, counts, offsets);
    hipLaunchKernelGGL(k_fill, dim3(NSAMP / 512), dim3(512), 0, stream, label, offsets, cursors, idx_list);
    hipLaunchKernelGGL(k_main, dim3(DIM / 1024, NCLS), dim3(256), 0, stream,
                       x, counts, offsets, idx_list, acc);
    hipLaunchKernelGGL(k_final, dim3(1), dim3(1), 0, stream, acc, out);
}